// Round 1
// baseline (779.856 us; speedup 1.0000x reference)
//
#include <hip/hip_runtime.h>
#include <hip/hip_bf16.h>
#include <math.h>

// Problem dims (fixed)
#define Bb 16
#define Hh 128
#define Ww 128
#define Cc 256
#define Kk 32
#define CLASSES 21
#define Nn (Hh*Ww)                  // 16384 pixels per batch
#define TILE 256                    // pixels per tile (== blockDim)
#define TILES_PER_BATCH (Nn/TILE)   // 64
#define BLOCKS_PER_BATCH 32
#define TILES_PER_BLOCK (TILES_PER_BATCH/BLOCKS_PER_BATCH) // 2
#define BN_EPS 1e-3f

// ws layout (floats)
#define WS_AGG  0                        // Bb*Kk*Cc = 131072
#define WS_WSUM (Bb*Kk*Cc)               // Bb*Kk = 512
#define WS_ATTN (WS_WSUM + Bb*Kk)        // Bb*Cc = 4096
#define WS_TOTAL (WS_ATTN + Bb*Cc)

// ---------------------------------------------------------------------------
// Kernel 1: fused distances -> softmax weights -> aggregation GEMM partials.
// Grid: Bb*BLOCKS_PER_BATCH blocks of 256 threads. Each block owns 2 tiles of
// 256 pixels of one batch. Phase 1: thread-per-pixel, codewords read with
// wave-uniform addresses (scalarizable), weights written to LDS transposed
// [k][n] (stride-1 across lanes -> conflict-free). Phase 2: thread-per-channel,
// coalesced x re-reads (L2-hot), w read as wave-uniform float4 broadcasts.
// agg partials live in registers across tiles; one atomicAdd per (k,c) at end.
// ---------------------------------------------------------------------------
__global__ __launch_bounds__(256, 2) void k_encode(
    const float* __restrict__ x, const float* __restrict__ cw,
    const float* __restrict__ smo, float* __restrict__ agg,
    float* __restrict__ wsum)
{
    __shared__ float w_lds[Kk][TILE];    // 32 KB, [k][n_local]
    __shared__ float sA[Kk], sB[Kk], sC[Kk]; // s[k], -2*s[k], c2[k]*s[k]

    const int tid = threadIdx.x;
    const int b   = blockIdx.x / BLOCKS_PER_BATCH;
    const int sub = blockIdx.x % BLOCKS_PER_BATCH;

    if (tid < Kk) {
        float c2 = 0.f;
        const float* row = cw + tid * Cc;
        for (int j = 0; j < Cc; j += 4) {
            float4 v = *(const float4*)(row + j);
            c2 += v.x*v.x + v.y*v.y + v.z*v.z + v.w*v.w;
        }
        float s = smo[tid];
        sA[tid] = s;
        sB[tid] = -2.f * s;
        sC[tid] = c2 * s;
    }

    float acc[Kk];
    float wsacc[Kk];
#pragma unroll
    for (int k = 0; k < Kk; ++k) { acc[k] = 0.f; wsacc[k] = 0.f; }

    __syncthreads();

    const float4* cw4 = (const float4*)cw;

    for (int tt = 0; tt < TILES_PER_BLOCK; ++tt) {
        const int tile = sub + tt * BLOCKS_PER_BATCH;
        const int n0   = tile * TILE;

        // ---------------- phase 1: softmax weights for pixel n0+tid ----------
        const float4* xrow = (const float4*)(x + ((size_t)b * Nn + n0 + tid) * Cc);
        float d[Kk];
#pragma unroll
        for (int k = 0; k < Kk; ++k) d[k] = 0.f;
        float x2 = 0.f;

        for (int j = 0; j < Cc/4; ++j) {
            float4 xv = xrow[j];
            x2 = fmaf(xv.x, xv.x, fmaf(xv.y, xv.y, fmaf(xv.z, xv.z, fmaf(xv.w, xv.w, x2))));
#pragma unroll
            for (int k = 0; k < Kk; ++k) {
                float4 cv = cw4[k * (Cc/4) + j];   // wave-uniform -> s_load
                d[k] = fmaf(xv.x, cv.x, fmaf(xv.y, cv.y, fmaf(xv.z, cv.z, fmaf(xv.w, cv.w, d[k]))));
            }
        }

        float m = -1e30f;
#pragma unroll
        for (int k = 0; k < Kk; ++k) {
            d[k] = fmaf(x2, sA[k], fmaf(d[k], sB[k], sC[k]));  // arg = dist*smo
            m = fmaxf(m, d[k]);
        }
        float sum = 0.f;
#pragma unroll
        for (int k = 0; k < Kk; ++k) { d[k] = __expf(d[k] - m); sum += d[k]; }
        float inv = 1.f / sum;
#pragma unroll
        for (int k = 0; k < Kk; ++k) w_lds[k][tid] = d[k] * inv; // stride-1 lanes

        __syncthreads();

        // ---------------- phase 2: agg[k][c] += sum_n w[n][k] * x[n][c] ------
        const int c = tid;
        const float* xin = x + ((size_t)b * Nn + n0) * Cc + c;
        for (int n4 = 0; n4 < TILE/4; ++n4) {
            float x0 = xin[(n4*4 + 0) * Cc];
            float x1 = xin[(n4*4 + 1) * Cc];
            float x2v = xin[(n4*4 + 2) * Cc];
            float x3 = xin[(n4*4 + 3) * Cc];
#pragma unroll
            for (int k = 0; k < Kk; ++k) {
                float4 wv = *(const float4*)&w_lds[k][n4*4]; // broadcast read
                acc[k] = fmaf(wv.x, x0, fmaf(wv.y, x1, fmaf(wv.z, x2v, fmaf(wv.w, x3, acc[k]))));
            }
        }

        // wave 0: wsum[k] partials for this tile
        if (tid < 64) {
#pragma unroll
            for (int k = 0; k < Kk; ++k) {
                float4 wv = *(const float4*)&w_lds[k][tid*4];
                float s = wv.x + wv.y + wv.z + wv.w;
#pragma unroll
                for (int off = 32; off; off >>= 1) s += __shfl_xor(s, off, 64);
                wsacc[k] += s;
            }
        }
        __syncthreads();
    }

    float* aggb = agg + (size_t)b * Kk * Cc;
#pragma unroll
    for (int k = 0; k < Kk; ++k) atomicAdd(aggb + k * Cc + tid, acc[k]);
    if (tid == 0) {
#pragma unroll
        for (int k = 0; k < Kk; ++k) atomicAdd(wsum + b * Kk + k, wsacc[k]);
    }
}

// ---------------------------------------------------------------------------
// Kernel 2: BN + ReLU + sum_k -> enc; attn = sigmoid(enc@W_enc+b);
// se = sigmoid(enc@W_se+b). One block per batch, thread-per-channel.
// ---------------------------------------------------------------------------
__global__ __launch_bounds__(256) void k_head(
    const float* __restrict__ agg, const float* __restrict__ wsum,
    const float* __restrict__ cw,
    const float* __restrict__ gamma, const float* __restrict__ beta,
    const float* __restrict__ mean, const float* __restrict__ var,
    const float* __restrict__ W_enc, const float* __restrict__ b_enc,
    const float* __restrict__ W_se, const float* __restrict__ b_se,
    float* __restrict__ attn, float* __restrict__ se_out)
{
    __shared__ float enc[Cc];
    const int b = blockIdx.x, c = threadIdx.x;

    float e = 0.f;
#pragma unroll
    for (int k = 0; k < Kk; ++k) {
        float a = agg[((size_t)b * Kk + k) * Cc + c] - wsum[b * Kk + k] * cw[k * Cc + c];
        float bnv = (a - mean[k]) * (1.0f / sqrtf(var[k] + BN_EPS)) * gamma[k] + beta[k];
        e += fmaxf(bnv, 0.f);
    }
    enc[c] = e;
    __syncthreads();

    float s = b_enc[c];
    for (int j = 0; j < Cc; ++j) s = fmaf(enc[j], W_enc[j * Cc + c], s);
    attn[b * Cc + c] = 1.f / (1.f + __expf(-s));

    if (c < CLASSES) {
        float q = b_se[c];
        for (int j = 0; j < Cc; ++j) q = fmaf(enc[j], W_se[j * CLASSES + c], q);
        se_out[b * CLASSES + c] = 1.f / (1.f + __expf(-q));
    }
}

// ---------------------------------------------------------------------------
// Kernel 3: featuremaps = attn[b,c] * inputs. Pure streaming, float4.
// ---------------------------------------------------------------------------
__global__ __launch_bounds__(256) void k_scale(
    const float4* __restrict__ xin, const float* __restrict__ attn,
    float4* __restrict__ out)
{
    const int total = Bb * Nn * Cc / 4;       // 16,777,216 float4
    int i = blockIdx.x * 256 + threadIdx.x;
    const int stride = gridDim.x * 256;
    for (; i < total; i += stride) {
        int b  = i >> 20;                     // Nn*Cc/4 = 2^20 per batch
        int c4 = i & (Cc/4 - 1);
        float4 a = *(const float4*)(attn + b * Cc + c4 * 4);
        float4 v = xin[i];
        v.x *= a.x; v.y *= a.y; v.z *= a.z; v.w *= a.w;
        out[i] = v;
    }
}

extern "C" void kernel_launch(void* const* d_in, const int* in_sizes, int n_in,
                              void* d_out, int out_size, void* d_ws, size_t ws_size,
                              hipStream_t stream)
{
    const float* x     = (const float*)d_in[0];
    const float* cw    = (const float*)d_in[1];
    const float* smo   = (const float*)d_in[2];
    const float* gamma = (const float*)d_in[3];
    const float* beta  = (const float*)d_in[4];
    const float* mean  = (const float*)d_in[5];
    const float* var   = (const float*)d_in[6];
    const float* W_enc = (const float*)d_in[7];
    const float* b_enc = (const float*)d_in[8];
    const float* W_se  = (const float*)d_in[9];
    const float* b_se  = (const float*)d_in[10];

    float* ws   = (float*)d_ws;
    float* agg  = ws + WS_AGG;
    float* wsum = ws + WS_WSUM;
    float* attn = ws + WS_ATTN;

    float* fm_out = (float*)d_out;
    float* se_out = fm_out + (size_t)Bb * Nn * Cc;

    hipMemsetAsync(d_ws, 0, WS_TOTAL * sizeof(float), stream);

    k_encode<<<Bb * BLOCKS_PER_BATCH, 256, 0, stream>>>(x, cw, smo, agg, wsum);
    k_head<<<Bb, Cc, 0, stream>>>(agg, wsum, cw, gamma, beta, mean, var,
                                  W_enc, b_enc, W_se, b_se, attn, se_out);
    k_scale<<<2048, 256, 0, stream>>>((const float4*)x, attn, (float4*)d_out);
}

// Round 2
// 633.572 us; speedup vs baseline: 1.2309x; 1.2309x over previous
//
#include <hip/hip_runtime.h>
#include <hip/hip_bf16.h>
#include <math.h>

// Problem dims (fixed)
#define Bb 16
#define Hh 128
#define Ww 128
#define Cc 256
#define Kk 32
#define CLASSES 21
#define Nn (Hh*Ww)                  // 16384 pixels per batch
#define TILE 256                    // pixels per block
#define BN_EPS 1e-3f

// ws layout (floats)
#define WS_AGG  0                        // Bb*Kk*Cc = 131072
#define WS_WSUM (Bb*Kk*Cc)               // Bb*Kk = 512
#define WS_ATTN (WS_WSUM + Bb*Kk)        // Bb*Cc = 4096
#define WS_TOTAL (WS_ATTN + Bb*Cc)

// ---------------------------------------------------------------------------
// k_encode v2: one 256-pixel tile per block (1024 blocks, 4/CU).
// Phase 1 (distances): x staged chunk-wise (32 ch) in LDS, swizzled so both
// the coalesced staging writes and the per-thread float4 compute reads are
// bank-conflict-free. Each thread owns 4 pixels x 8 codewords in registers.
// Softmax: args round-trip through the reused xs region ([k][px]); thread-
// per-pixel normalizes. Phase 2 (aggregation): wave w handles k-half (w&1)
// and n-half (w>>1); thread owns 4 channels x 16 k in registers; w read as
// wave-uniform float4 broadcasts from LDS. Partials atomicAdd'ed to agg.
// ---------------------------------------------------------------------------
__global__ __launch_bounds__(256, 4) void k_encode(
    const float* __restrict__ x, const float* __restrict__ cw,
    const float* __restrict__ smo, float* __restrict__ agg,
    float* __restrict__ wsum)
{
    __shared__ float xs[32 * 256];      // 32 KB: x chunk [c][q] (later: warr [k][px])
    __shared__ float cs[32][32];        // 4 KB: cw chunk [c][k]
    __shared__ float sA[Kk], sB[Kk], sC[Kk];
    __shared__ float wsumS[Kk];

    const int tid  = threadIdx.x;
    const int lane = tid & 63;
    const int wv   = tid >> 6;
    const int b    = blockIdx.x >> 6;   // 64 tiles per batch
    const int tile = blockIdx.x & 63;
    const int n0   = tile * TILE;
    const float* xb = x + ((size_t)b * Nn + n0) * Cc;

    if (tid < Kk) {
        float c2 = 0.f;
        const float4* row = (const float4*)(cw + tid * Cc);
        for (int j = 0; j < Cc/4; ++j) {
            float4 v = row[j];
            c2 += v.x*v.x + v.y*v.y + v.z*v.z + v.w*v.w;
        }
        float s = smo[tid];
        sA[tid] = s; sB[tid] = -2.f * s; sC[tid] = c2 * s;
        wsumS[tid] = 0.f;
    }

    // ---------------- phase 1: d[k] = x . c_k for 4 pixels x 8 k ------------
    const int px0 = (tid & 63) * 4;     // 4 consecutive pixels
    const int k0  = (tid >> 6) * 8;     // 8 codewords (wave-uniform)
    float4 d4[8];
    float4 x2v = make_float4(0.f, 0.f, 0.f, 0.f);
#pragma unroll
    for (int j = 0; j < 8; ++j) d4[j] = make_float4(0.f, 0.f, 0.f, 0.f);

    for (int ch = 0; ch < 8; ++ch) {
        const int c0 = ch * 32;
        __syncthreads();                 // previous chunk fully consumed
        // stage cw chunk transposed: cs[c][k]
        {
            int k  = tid & 31;
            int cb = (tid >> 5) << 2;    // 0,4,...,28
            const float* src = cw + k * Cc + c0 + cb;
            cs[cb+0][k] = src[0];
            cs[cb+1][k] = src[1];
            cs[cb+2][k] = src[2];
            cs[cb+3][k] = src[3];
        }
        // stage x chunk: coalesced float4 loads, swizzled scalar LDS writes
#pragma unroll
        for (int i = 0; i < 8; ++i) {
            int f  = tid + (i << 8);     // 0..2047
            int p  = f >> 3;             // pixel 0..255
            int c4 = f & 7;              // which float4 of the 32-ch chunk
            float4 v = *(const float4*)(xb + (size_t)p * Cc + c0 + (c4 << 2));
            int q = (p + (c4 << 2)) & 255;   // swizzle: distinct banks per lane
            xs[(4*c4 + 0) * 256 + q] = v.x;
            xs[(4*c4 + 1) * 256 + q] = v.y;
            xs[(4*c4 + 2) * 256 + q] = v.z;
            xs[(4*c4 + 3) * 256 + q] = v.w;
        }
        __syncthreads();
        // compute: per channel, 1 b128 x-read + 2 b128 cw broadcasts + 36 FMA
#pragma unroll
        for (int c = 0; c < 32; ++c) {
            int q = (px0 + ((c >> 2) << 2)) & 255;    // matches staging swizzle
            float4 xv = *(const float4*)&xs[c * 256 + q];
            x2v.x = fmaf(xv.x, xv.x, x2v.x);
            x2v.y = fmaf(xv.y, xv.y, x2v.y);
            x2v.z = fmaf(xv.z, xv.z, x2v.z);
            x2v.w = fmaf(xv.w, xv.w, x2v.w);
            float4 ck0 = *(const float4*)&cs[c][k0];
            float4 ck1 = *(const float4*)&cs[c][k0 + 4];
            const float ck[8] = {ck0.x, ck0.y, ck0.z, ck0.w, ck1.x, ck1.y, ck1.z, ck1.w};
#pragma unroll
            for (int j = 0; j < 8; ++j) {
                d4[j].x = fmaf(xv.x, ck[j], d4[j].x);
                d4[j].y = fmaf(xv.y, ck[j], d4[j].y);
                d4[j].z = fmaf(xv.z, ck[j], d4[j].z);
                d4[j].w = fmaf(xv.w, ck[j], d4[j].w);
            }
        }
    }

    // ---------------- softmax args -> LDS (reuse xs as warr[k][px]) ---------
    __syncthreads();
    float* warr = xs;
#pragma unroll
    for (int j = 0; j < 8; ++j) {
        int k = k0 + j;
        float4 a;
        a.x = fmaf(x2v.x, sA[k], fmaf(d4[j].x, sB[k], sC[k]));
        a.y = fmaf(x2v.y, sA[k], fmaf(d4[j].y, sB[k], sC[k]));
        a.z = fmaf(x2v.z, sA[k], fmaf(d4[j].z, sB[k], sC[k]));
        a.w = fmaf(x2v.w, sA[k], fmaf(d4[j].w, sB[k], sC[k]));
        *(float4*)&warr[k * 256 + px0] = a;
    }
    __syncthreads();

    // ---------------- softmax: thread-per-pixel -----------------------------
    {
        float v[Kk];
        float m = -3.4e38f;
#pragma unroll
        for (int k = 0; k < Kk; ++k) { v[k] = warr[k * 256 + tid]; m = fmaxf(m, v[k]); }
        float sum = 0.f;
#pragma unroll
        for (int k = 0; k < Kk; ++k) { v[k] = __expf(v[k] - m); sum += v[k]; }
        float inv = 1.f / sum;
#pragma unroll
        for (int k = 0; k < Kk; ++k) {
            float wk = v[k] * inv;
            warr[k * 256 + tid] = wk;
            float r = wk;
#pragma unroll
            for (int off = 32; off; off >>= 1) r += __shfl_xor(r, off, 64);
            if (lane == 0) atomicAdd(&wsumS[k], r);
        }
    }
    __syncthreads();
    if (tid < Kk) atomicAdd(wsum + b * Kk + tid, wsumS[tid]);

    // ---------------- phase 2: agg[k][c] += sum_n w[n][k] x[n][c] -----------
    const int kh = wv & 1;               // k-half
    const int nh = wv >> 1;              // n-half
    const int kb = kh * 16;
    float acc[4][16];
#pragma unroll
    for (int j = 0; j < 4; ++j)
#pragma unroll
        for (int kk = 0; kk < 16; ++kk) acc[j][kk] = 0.f;

    for (int n4 = 0; n4 < 32; ++n4) {
        const int n = nh * 128 + n4 * 4;
        float xr[4][4];                  // [n-sub][c-group]
#pragma unroll
        for (int i = 0; i < 4; ++i) {
            const float* xrow = xb + (size_t)(n + i) * Cc + lane;
            xr[i][0] = xrow[0];
            xr[i][1] = xrow[64];
            xr[i][2] = xrow[128];
            xr[i][3] = xrow[192];
        }
#pragma unroll
        for (int kk = 0; kk < 16; ++kk) {
            float4 wv4 = *(const float4*)&warr[(kb + kk) * 256 + n];  // broadcast
#pragma unroll
            for (int j = 0; j < 4; ++j) {
                acc[j][kk] = fmaf(wv4.x, xr[0][j],
                             fmaf(wv4.y, xr[1][j],
                             fmaf(wv4.z, xr[2][j],
                             fmaf(wv4.w, xr[3][j], acc[j][kk]))));
            }
        }
    }

    float* aggb = agg + ((size_t)b * Kk + kb) * Cc;
#pragma unroll
    for (int kk = 0; kk < 16; ++kk)
#pragma unroll
        for (int j = 0; j < 4; ++j)
            atomicAdd(aggb + kk * Cc + lane + 64 * j, acc[j][kk]);
}

// ---------------------------------------------------------------------------
// Kernel 2: BN + ReLU + sum_k -> enc; attn = sigmoid(enc@W_enc+b);
// se = sigmoid(enc@W_se+b). One block per batch, thread-per-channel.
// ---------------------------------------------------------------------------
__global__ __launch_bounds__(256) void k_head(
    const float* __restrict__ agg, const float* __restrict__ wsum,
    const float* __restrict__ cw,
    const float* __restrict__ gamma, const float* __restrict__ beta,
    const float* __restrict__ mean, const float* __restrict__ var,
    const float* __restrict__ W_enc, const float* __restrict__ b_enc,
    const float* __restrict__ W_se, const float* __restrict__ b_se,
    float* __restrict__ attn, float* __restrict__ se_out)
{
    __shared__ float enc[Cc];
    const int b = blockIdx.x, c = threadIdx.x;

    float e = 0.f;
#pragma unroll
    for (int k = 0; k < Kk; ++k) {
        float a = agg[((size_t)b * Kk + k) * Cc + c] - wsum[b * Kk + k] * cw[k * Cc + c];
        float bnv = (a - mean[k]) * (1.0f / sqrtf(var[k] + BN_EPS)) * gamma[k] + beta[k];
        e += fmaxf(bnv, 0.f);
    }
    enc[c] = e;
    __syncthreads();

    float s = b_enc[c];
    for (int j = 0; j < Cc; ++j) s = fmaf(enc[j], W_enc[j * Cc + c], s);
    attn[b * Cc + c] = 1.f / (1.f + __expf(-s));

    if (c < CLASSES) {
        float q = b_se[c];
        for (int j = 0; j < Cc; ++j) q = fmaf(enc[j], W_se[j * CLASSES + c], q);
        se_out[b * CLASSES + c] = 1.f / (1.f + __expf(-q));
    }
}

// ---------------------------------------------------------------------------
// Kernel 3: featuremaps = attn[b,c] * inputs. Pure streaming, float4.
// ---------------------------------------------------------------------------
__global__ __launch_bounds__(256) void k_scale(
    const float4* __restrict__ xin, const float* __restrict__ attn,
    float4* __restrict__ out)
{
    const int total = Bb * Nn * Cc / 4;       // 16,777,216 float4
    int i = blockIdx.x * 256 + threadIdx.x;
    const int stride = gridDim.x * 256;
    for (; i < total; i += stride) {
        int b  = i >> 20;                     // Nn*Cc/4 = 2^20 per batch
        int c4 = i & (Cc/4 - 1);
        float4 a = *(const float4*)(attn + b * Cc + c4 * 4);
        float4 v = xin[i];
        v.x *= a.x; v.y *= a.y; v.z *= a.z; v.w *= a.w;
        out[i] = v;
    }
}

extern "C" void kernel_launch(void* const* d_in, const int* in_sizes, int n_in,
                              void* d_out, int out_size, void* d_ws, size_t ws_size,
                              hipStream_t stream)
{
    const float* x     = (const float*)d_in[0];
    const float* cw    = (const float*)d_in[1];
    const float* smo   = (const float*)d_in[2];
    const float* gamma = (const float*)d_in[3];
    const float* beta  = (const float*)d_in[4];
    const float* mean  = (const float*)d_in[5];
    const float* var   = (const float*)d_in[6];
    const float* W_enc = (const float*)d_in[7];
    const float* b_enc = (const float*)d_in[8];
    const float* W_se  = (const float*)d_in[9];
    const float* b_se  = (const float*)d_in[10];

    float* ws   = (float*)d_ws;
    float* agg  = ws + WS_AGG;
    float* wsum = ws + WS_WSUM;
    float* attn = ws + WS_ATTN;

    float* fm_out = (float*)d_out;
    float* se_out = fm_out + (size_t)Bb * Nn * Cc;

    hipMemsetAsync(d_ws, 0, WS_TOTAL * sizeof(float), stream);

    k_encode<<<Bb * 64, 256, 0, stream>>>(x, cw, smo, agg, wsum);
    k_head<<<Bb, Cc, 0, stream>>>(agg, wsum, cw, gamma, beta, mean, var,
                                  W_enc, b_enc, W_se, b_se, attn, se_out);
    k_scale<<<2048, 256, 0, stream>>>((const float4*)x, attn, (float4*)d_out);
}

// Round 3
// 632.627 us; speedup vs baseline: 1.2327x; 1.0015x over previous
//
#include <hip/hip_runtime.h>
#include <hip/hip_bf16.h>
#include <math.h>

#define Bb 16
#define Cc 256
#define Kk 32
#define CLASSES 21
#define Nn 16384
#define BN_EPS 1e-3f

// ws layout (floats)
#define WS_AGG  0                         // Bb*Kk*Cc = 131072
#define WS_WSUM (Bb*Kk*Cc)                // Bb*Kk = 512
#define WS_ATTN (WS_WSUM + Bb*Kk)         // Bb*Cc = 4096
#define WS_ENC  (WS_ATTN + Bb*Cc)         // Bb*Cc = 4096

typedef float  f32x4  __attribute__((ext_vector_type(4)));
typedef short  short8 __attribute__((ext_vector_type(8)));
typedef unsigned int u32;

union Frag { u32 u[4]; short8 s; };

// truncation-split: a = hi + lo with hi,lo bf16-representable; dropped residue ~2^-16|a|
__device__ inline void split2(float a, float b, u32& h, u32& l) {
    u32 ba = __float_as_uint(a), bb = __float_as_uint(b);
    float fa = __uint_as_float(ba & 0xFFFF0000u);
    float fb = __uint_as_float(bb & 0xFFFF0000u);
    float la = a - fa, lb = b - fb;
    h = (ba >> 16) | (bb & 0xFFFF0000u);
    l = (__float_as_uint(la) >> 16) | (__float_as_uint(lb) & 0xFFFF0000u);
}
__device__ inline void split8(f32x4 v0, f32x4 v1, Frag& h, Frag& l) {
    split2(v0[0], v0[1], h.u[0], l.u[0]);
    split2(v0[2], v0[3], h.u[1], l.u[1]);
    split2(v1[0], v1[1], h.u[2], l.u[2]);
    split2(v1[2], v1[3], h.u[3], l.u[3]);
}

// ---------------------------------------------------------------------------
// k_encode v3 (full MFMA): 1024 blocks (16 b x 64 tiles of 256 px), 256 thr.
// Per 64-px subtile: stage x once (A-frags in regs + fp32 transposed xt in
// LDS), phase-1 D1[px][k] = x.cw^T via 3-product bf16-split MFMA, in-register
// softmax (C/D map: col=lane&15, row=(lane>>4)*4+reg), W -> swizzled bf16
// hi/lo LDS, phase-2 D2[c][k] = x^T.W via MFMA accumulated in AGPRs across
// subtiles. Epilogue: one atomicAdd per (k,c) partial.
// ---------------------------------------------------------------------------
__global__ __launch_bounds__(256, 2) void k_encode(
    const float* __restrict__ x, const float* __restrict__ cw,
    const float* __restrict__ smo, float* __restrict__ agg,
    float* __restrict__ wsum)
{
    __shared__ __align__(16) float xt[Cc][68];            // 69.6 KB, pad 68 vs 64
    __shared__ __align__(16) unsigned short wh[Kk * 64];  // 4 KB, swizzled
    __shared__ __align__(16) unsigned short wl[Kk * 64];  // 4 KB
    __shared__ float sA[Kk], sB[Kk], sC[Kk];

    const int tid  = threadIdx.x;
    const int lane = tid & 63;
    const int wv   = tid >> 6;
    const int b    = blockIdx.x >> 6;
    const int tile = blockIdx.x & 63;
    const int l15  = lane & 15;
    const int lg   = lane >> 4;

    if (tid < Kk) {
        float c2 = 0.f;
        const f32x4* row = (const f32x4*)(cw + tid * Cc);
        for (int j = 0; j < Cc/4; ++j) {
            f32x4 v = row[j];
            c2 += v[0]*v[0] + v[1]*v[1] + v[2]*v[2] + v[3]*v[3];
        }
        float s = smo[tid];
        sA[tid] = s; sB[tid] = -2.f * s; sC[tid] = c2 * s;
    }

    f32x4 acc2[4][2];
#pragma unroll
    for (int mi = 0; mi < 4; ++mi)
#pragma unroll
        for (int nt = 0; nt < 2; ++nt)
#pragma unroll
            for (int r = 0; r < 4; ++r) acc2[mi][nt][r] = 0.f;

    for (int sub = 0; sub < 4; ++sub) {
        __syncthreads();   // prev phase-2 done (and sA/sB/sC ready on sub=0)

        // ---------------- staging: x -> A-frags (regs) + xt (LDS) -----------
        const int pxl = l15 + 16 * wv;    // this thread's px row within subtile
        const float* xsub = x + ((size_t)b * Nn + tile * 256 + sub * 64 + pxl) * Cc;
        Frag ah[8], al[8];
        float x2p = 0.f;
#pragma unroll
        for (int kc = 0; kc < 8; ++kc) {
            const int g = kc * 32 + lg * 8;          // channel base for this lane-group
            f32x4 v0 = *(const f32x4*)(xsub + g);
            f32x4 v1 = *(const f32x4*)(xsub + g + 4);
            x2p = fmaf(v0[0],v0[0],fmaf(v0[1],v0[1],fmaf(v0[2],v0[2],fmaf(v0[3],v0[3],x2p))));
            x2p = fmaf(v1[0],v1[0],fmaf(v1[1],v1[1],fmaf(v1[2],v1[2],fmaf(v1[3],v1[3],x2p))));
            split8(v0, v1, ah[kc], al[kc]);
#pragma unroll
            for (int e = 0; e < 4; ++e) {
                xt[g + e][pxl]     = v0[e];
                xt[g + 4 + e][pxl] = v1[e];
            }
        }

        // ---------------- phase 1: D1[px][k] via MFMA -----------------------
        f32x4 acc1[2];
#pragma unroll
        for (int nt = 0; nt < 2; ++nt)
#pragma unroll
            for (int r = 0; r < 4; ++r) acc1[nt][r] = 0.f;

#pragma unroll
        for (int kc = 0; kc < 8; ++kc) {
#pragma unroll
            for (int nt = 0; nt < 2; ++nt) {
                const int k = l15 + 16 * nt;
                const float* cr = cw + k * Cc + kc * 32 + lg * 8;
                f32x4 c0 = *(const f32x4*)cr;
                f32x4 c1 = *(const f32x4*)(cr + 4);
                Frag bh, bl; split8(c0, c1, bh, bl);
                acc1[nt] = __builtin_amdgcn_mfma_f32_16x16x32_bf16(ah[kc].s, bh.s, acc1[nt], 0, 0, 0);
                acc1[nt] = __builtin_amdgcn_mfma_f32_16x16x32_bf16(al[kc].s, bh.s, acc1[nt], 0, 0, 0);
                acc1[nt] = __builtin_amdgcn_mfma_f32_16x16x32_bf16(ah[kc].s, bl.s, acc1[nt], 0, 0, 0);
            }
        }

        // ---------------- softmax (in-register) -----------------------------
        x2p += __shfl_xor(x2p, 16, 64);
        x2p += __shfl_xor(x2p, 32, 64);          // full x2 for px row pxl
        float x2r[4];
#pragma unroll
        for (int r = 0; r < 4; ++r) x2r[r] = __shfl(x2p, lg * 4 + r, 64);

        f32x4 arg[2];
#pragma unroll
        for (int nt = 0; nt < 2; ++nt) {
            const int k = l15 + 16 * nt;
            const float a_ = sA[k], b_ = sB[k], c_ = sC[k];
#pragma unroll
            for (int r = 0; r < 4; ++r)
                arg[nt][r] = fmaf(x2r[r], a_, fmaf(acc1[nt][r], b_, c_));
        }
        f32x4 mx;
#pragma unroll
        for (int r = 0; r < 4; ++r) mx[r] = fmaxf(arg[0][r], arg[1][r]);
#pragma unroll
        for (int off = 1; off <= 8; off <<= 1)
#pragma unroll
            for (int r = 0; r < 4; ++r) mx[r] = fmaxf(mx[r], __shfl_xor(mx[r], off, 64));

        f32x4 e0, e1, es;
#pragma unroll
        for (int r = 0; r < 4; ++r) {
            e0[r] = __expf(arg[0][r] - mx[r]);
            e1[r] = __expf(arg[1][r] - mx[r]);
            es[r] = e0[r] + e1[r];
        }
#pragma unroll
        for (int off = 1; off <= 8; off <<= 1)
#pragma unroll
            for (int r = 0; r < 4; ++r) es[r] += __shfl_xor(es[r], off, 64);

        float sw[2] = {0.f, 0.f};
#pragma unroll
        for (int r = 0; r < 4; ++r) {
            const float inv = 1.f / es[r];
            const int px = lg * 4 + r + 16 * wv;         // px within subtile
#pragma unroll
            for (int nt = 0; nt < 2; ++nt) {
                const int k = l15 + 16 * nt;
                const float w = (nt ? e1[r] : e0[r]) * inv;
                sw[nt] += w;
                const int pxs = (px & 7) | ((((px >> 3) & 7) ^ (k & 7)) << 3);
                const u32 wb = __float_as_uint(w);
                const float whf = __uint_as_float(wb & 0xFFFF0000u);
                wh[k * 64 + pxs] = (unsigned short)(wb >> 16);
                wl[k * 64 + pxs] = (unsigned short)(__float_as_uint(w - whf) >> 16);
            }
        }
#pragma unroll
        for (int nt = 0; nt < 2; ++nt) {
            sw[nt] += __shfl_xor(sw[nt], 16, 64);
            sw[nt] += __shfl_xor(sw[nt], 32, 64);
        }
        if (lane < 16) {
            atomicAdd(wsum + b * Kk + lane,      sw[0]);
            atomicAdd(wsum + b * Kk + lane + 16, sw[1]);
        }
        __syncthreads();   // wh/wl + xt ready

        // ---------------- phase 2: D2[c][k] += x^T . W ----------------------
#pragma unroll
        for (int kc2 = 0; kc2 < 2; ++kc2) {
            Frag bwh[2], bwl[2];
#pragma unroll
            for (int nt = 0; nt < 2; ++nt) {
                const int k = l15 + 16 * nt;
                const int u = (kc2 * 4 + lg) ^ (k & 7);
                bwh[nt] = *(const Frag*)&wh[k * 64 + u * 8];
                bwl[nt] = *(const Frag*)&wl[k * 64 + u * 8];
            }
#pragma unroll
            for (int mi = 0; mi < 4; ++mi) {
                const int c = wv * 64 + mi * 16 + l15;
                const int px0 = kc2 * 32 + lg * 8;
                f32x4 v0 = *(const f32x4*)&xt[c][px0];
                f32x4 v1 = *(const f32x4*)&xt[c][px0 + 4];
                Frag xh, xl; split8(v0, v1, xh, xl);
#pragma unroll
                for (int nt = 0; nt < 2; ++nt) {
                    acc2[mi][nt] = __builtin_amdgcn_mfma_f32_16x16x32_bf16(xh.s, bwh[nt].s, acc2[mi][nt], 0, 0, 0);
                    acc2[mi][nt] = __builtin_amdgcn_mfma_f32_16x16x32_bf16(xl.s, bwh[nt].s, acc2[mi][nt], 0, 0, 0);
                    acc2[mi][nt] = __builtin_amdgcn_mfma_f32_16x16x32_bf16(xh.s, bwl[nt].s, acc2[mi][nt], 0, 0, 0);
                }
            }
        }
    }

    // ---------------- epilogue: agg partials ------------------------------
    float* aggb = agg + (size_t)b * Kk * Cc;
#pragma unroll
    for (int mi = 0; mi < 4; ++mi)
#pragma unroll
        for (int nt = 0; nt < 2; ++nt) {
            const int k = l15 + 16 * nt;
            const int cbase = wv * 64 + mi * 16 + lg * 4;
#pragma unroll
            for (int r = 0; r < 4; ++r)
                atomicAdd(aggb + k * Cc + cbase + r, acc2[mi][nt][r]);
        }
}

// ---------------------------------------------------------------------------
// k_enc: enc[b][c] = sum_k relu(bn(agg - wsum*cw)); also se head. 16 blocks.
// ---------------------------------------------------------------------------
__global__ __launch_bounds__(256) void k_enc(
    const float* __restrict__ agg, const float* __restrict__ wsum,
    const float* __restrict__ cw,
    const float* __restrict__ gamma, const float* __restrict__ beta,
    const float* __restrict__ mean, const float* __restrict__ var,
    const float* __restrict__ W_se, const float* __restrict__ b_se,
    float* __restrict__ enc_out, float* __restrict__ se_out)
{
    __shared__ float enc[Cc];
    __shared__ float red[4 * CLASSES];
    const int b = blockIdx.x, c = threadIdx.x;

    float e = 0.f;
#pragma unroll
    for (int k = 0; k < Kk; ++k) {
        float a = agg[((size_t)b * Kk + k) * Cc + c] - wsum[b * Kk + k] * cw[k * Cc + c];
        float bnv = (a - mean[k]) * rsqrtf(var[k] + BN_EPS) * gamma[k] + beta[k];
        e += fmaxf(bnv, 0.f);
    }
    enc[c] = e;
    enc_out[b * Cc + c] = e;
    __syncthreads();

    if (c < 4 * CLASSES) {
        const int cls = c % CLASSES, p = c / CLASSES;
        float q = 0.f;
        for (int j = p * 64; j < p * 64 + 64; ++j)
            q = fmaf(enc[j], W_se[j * CLASSES + cls], q);
        red[c] = q;
    }
    __syncthreads();
    if (c < CLASSES) {
        float s = red[c] + red[c + CLASSES] + red[c + 2*CLASSES] + red[c + 3*CLASSES] + b_se[c];
        se_out[b * CLASSES + c] = 1.f / (1.f + __expf(-s));
    }
}

// ---------------------------------------------------------------------------
// k_attn: attn[b][c] = sigmoid(enc @ W_enc + b). 64 blocks (16 b x 4 chunks).
// ---------------------------------------------------------------------------
__global__ __launch_bounds__(256) void k_attn(
    const float* __restrict__ enc, const float* __restrict__ W_enc,
    const float* __restrict__ b_enc, float* __restrict__ attn)
{
    __shared__ float red[4][64];
    const int b = blockIdx.x >> 2, cq = blockIdx.x & 3;
    const int cl = threadIdx.x & 63, jq = threadIdx.x >> 6;
    const int c = cq * 64 + cl;
    const float* eb = enc + b * Cc;

    float q = 0.f;
    for (int j = jq * 64; j < jq * 64 + 64; ++j)
        q = fmaf(eb[j], W_enc[j * Cc + c], q);
    red[jq][cl] = q;
    __syncthreads();
    if (threadIdx.x < 64) {
        float s = red[0][threadIdx.x] + red[1][threadIdx.x] + red[2][threadIdx.x]
                + red[3][threadIdx.x] + b_enc[cq * 64 + threadIdx.x];
        attn[b * Cc + cq * 64 + threadIdx.x] = 1.f / (1.f + __expf(-s));
    }
}

// ---------------------------------------------------------------------------
// k_scale: featuremaps = attn[b,c] * inputs. attn hoisted out of the loop.
// ---------------------------------------------------------------------------
__global__ __launch_bounds__(256) void k_scale(
    const float4* __restrict__ xin, const float* __restrict__ attn,
    float4* __restrict__ out)
{
    const int b = blockIdx.x >> 8, chunk = blockIdx.x & 255;
    const float4 a = *(const float4*)(attn + b * Cc + (threadIdx.x & 63) * 4);
    size_t base = (size_t)b * (Nn * Cc / 4) + chunk * 4096 + threadIdx.x;
#pragma unroll
    for (int it = 0; it < 16; ++it) {
        size_t idx = base + it * 256;
        float4 v = xin[idx];
        v.x *= a.x; v.y *= a.y; v.z *= a.z; v.w *= a.w;
        out[idx] = v;
    }
}

extern "C" void kernel_launch(void* const* d_in, const int* in_sizes, int n_in,
                              void* d_out, int out_size, void* d_ws, size_t ws_size,
                              hipStream_t stream)
{
    const float* x     = (const float*)d_in[0];
    const float* cw    = (const float*)d_in[1];
    const float* smo   = (const float*)d_in[2];
    const float* gamma = (const float*)d_in[3];
    const float* beta  = (const float*)d_in[4];
    const float* mean  = (const float*)d_in[5];
    const float* var   = (const float*)d_in[6];
    const float* W_enc = (const float*)d_in[7];
    const float* b_enc = (const float*)d_in[8];
    const float* W_se  = (const float*)d_in[9];
    const float* b_se  = (const float*)d_in[10];

    float* ws   = (float*)d_ws;
    float* agg  = ws + WS_AGG;
    float* wsum = ws + WS_WSUM;
    float* attn = ws + WS_ATTN;
    float* enc  = ws + WS_ENC;

    float* fm_out = (float*)d_out;
    float* se_out = fm_out + (size_t)Bb * Nn * Cc;

    hipMemsetAsync(d_ws, 0, (size_t)(Bb * Kk * Cc + Bb * Kk) * sizeof(float), stream);

    k_encode<<<Bb * 64, 256, 0, stream>>>(x, cw, smo, agg, wsum);
    k_enc<<<Bb, 256, 0, stream>>>(agg, wsum, cw, gamma, beta, mean, var,
                                  W_se, b_se, enc, se_out);
    k_attn<<<Bb * 4, 256, 0, stream>>>(enc, W_enc, b_enc, attn);
    k_scale<<<Bb * 256, 256, 0, stream>>>((const float4*)x, attn, (float4*)d_out);
}